// Round 2
// baseline (835.518 us; speedup 1.0000x reference)
//
#include <hip/hip_runtime.h>
#include <math.h>

#define D_DIM 2048
#define T_DIM 128
#define TT 8    // t-values per pass (two passes per block -> 16 t per block)

// TT=8 swizzles: tt supplies only 3 bank bits, so XOR TWO row bits into
// e' bits 0,1 (bank bits 3,4).  Both are involutions; write & read use the
// same swizzle so the mapping stays consistent.
// T1: e' layout write=(j<<5)|r (r in bits 0..4), read=j|(r<<5) (r in 5..9)
//     -> XOR bits 0,1 with bits 5,6: varies with r on the read side,
//        varies with j (const/instr) on the write side where r already
//        sits in bits 0,1.  Both sides <=2-way.
__device__ __forceinline__ int sw1(int x) { return x ^ ((x >> 5) & 3); }
// T2/T3: r sits in bits 4..8 on one side, bits 0..3 on the other
//     -> XOR bits 0,1 with bits 4,5.  Both sides <=2-way.
__device__ __forceinline__ int sw2(int x) { return x ^ ((x >> 4) & 3); }

// radix-2 butterfly over register-index bit MM (fully unrolled, constant idx)
#define BFLY(MM)                                              \
    _Pragma("unroll")                                         \
    for (int i_ = 0; i_ < 64; ++i_) {                         \
        if ((i_ & (MM)) == 0) {                               \
            float a_ = v[i_], b_ = v[i_ | (MM)];              \
            v[i_] = a_ + b_;                                  \
            v[i_ | (MM)] = a_ - b_;                           \
        }                                                     \
    }

// 256 threads, 32 KiB LDS -> 5 blocks/CU (LDS-limited), 20 waves/CU.
// (256,4): 4 waves/EU min -> 128-VGPR cap; kernel needs ~80, no spill.
__global__ __launch_bounds__(256, 4)
void fwht_apply_kernel(const float* __restrict__ z,
                       const float* __restrict__ d1,
                       const float* __restrict__ d2,
                       const float* __restrict__ d3,
                       const float* __restrict__ bvec,
                       const float* __restrict__ sldj_in,
                       float* __restrict__ out) {
    __shared__ float lds[1024 * TT];            // 32 KiB
    const int tid = threadIdx.x;

    if (blockIdx.x == 1024) {                   // ---- sldj block ----
        float acc = 0.0f;
        for (int i = tid; i < D_DIM; i += 256)
            acc += logf(fabsf(d1[i])) + logf(fabsf(d2[i])) + logf(fabsf(d3[i]));
        lds[tid] = acc;
        __syncthreads();
        #pragma unroll
        for (int sft = 128; sft > 0; sft >>= 1) {
            if (tid < sft) lds[tid] += lds[tid + sft];
            __syncthreads();
        }
        if (tid < 128)
            out[(size_t)4 * 32 * 2048 * 128 + tid] = sldj_in[tid] + lds[0];
        return;
    }

    const int r   = tid >> 3;                   // 5-bit "rest" coordinate (0..31)
    const int tt  = tid & 7;                    // t within tile (0..7)
    const int bid = blockIdx.x;
    // km in LOW bits: all 8 pair-blocks of a km slab share bid%8 -> same XCD,
    // so every 128B line of the slab is read/written through ONE L2.
    const int km  = bid & 127;                  // (k,m) slab (128 total)
    const int p0  = bid >> 7;                   // tile-pair index (0..7)
    const float s = 0.022097086912079608f;      // 1/sqrt(2048), one per H

    const int wid  = tid >> 6;                  // wave id (0..3)
    const int lane = tid & 63;
    const int q    = (lane >> 1) & 15;          // 4-bit row-within-run
    const int c    = lane & 1;                  // float4 slot within 32B row
    const int nl   = lane >> 5;                 // run lsb from lane bit5

    // Two passes: tiles 2*p0 and 2*p0+1.  The passes touch the two 32B
    // halves of each 64B line from the same block (same XCD L2, adjacent
    // in time) so HBM reads/writebacks stay full-line.
    #pragma unroll 1
    for (int p = 0; p < 2; ++p) {
        const int t0 = (p0 << 4) | (p << 3);    // tile base (16 tiles of 8)
        const float* zslab = z + ((size_t)km << 18) + t0;
        float v[64];
        __syncthreads();                        // LDS reuse across passes

        // ---- staged load: two 32KiB rounds partitioned by e-bit4.
        // Global: dwordx4, 32 rows x 32B fully-used per wave-instruction.
        // LDS row idx = (e>>5)<<4 | (e&15); word = idx*8 + t.  b128 writes
        // land at word = 4*lane (+n<<7) -> linear, conflict-free.
        #pragma unroll
        for (int h = 0; h < 2; ++h) {
            #pragma unroll
            for (int i = 0; i < 8; ++i) {
                const int n = (wid << 4) | (i << 1) | nl;   // run (0..63)
                const int e = (n << 5) | (h << 4) | q;
                float4 tmp = *(const float4*)(zslab + (size_t)e * T_DIM + (c << 2));
                ((float4*)lds)[(n << 5) + (q << 1) + c] = tmp;
            }
            __syncthreads();
            if (((r >> 4) & 1) == h) {
                // P1 read: word = j<<7 | (r&15)<<3 | tt.
                // bank = (r&3)<<3 | tt -> 32 banks over (tt,r0,r1), r2 2-way.
                #pragma unroll
                for (int j = 0; j < 64; ++j) {
                    const int e = (j << 5) | r;
                    v[j] = lds[(j << 7) + ((r & 15) << 3) + tt] * (d1[e] * s);
                }
            }
            __syncthreads();
        }

        // ---- P1: e = (j<<5)|r.  F1 on e-bits 5..10 ----
        BFLY(1) BFLY(2) BFLY(4) BFLY(8) BFLY(16) BFLY(32)

        // ---- T1: partition e-bit10 (= j5 on both sides). e' = e & 1023 ----
        #pragma unroll
        for (int j = 0; j < 32; ++j)                      // round A write (e10=0)
            lds[(sw1((j << 5) | r) << 3) + tt] = v[j];
        __syncthreads();
        #pragma unroll
        for (int j = 0; j < 32; ++j)                      // round A read: P2 map
            v[j] = lds[(sw1(j | (r << 5)) << 3) + tt];
        __syncthreads();
        #pragma unroll
        for (int j = 32; j < 64; ++j)                     // round B write (e10=1)
            lds[(sw1(((j & 31) << 5) | r) << 3) + tt] = v[j];
        __syncthreads();
        #pragma unroll
        for (int j = 32; j < 64; ++j)                     // round B read
            v[j] = lds[(sw1((j & 31) | (r << 5)) << 3) + tt];
        __syncthreads();

        // ---- P2: e = (j&31) | ((j>>5)<<10) | (r<<5) ----
        BFLY(1) BFLY(2) BFLY(4) BFLY(8) BFLY(16)          // F1 e-bits 0..4 (F1 done)
        {   // * d2 * s : per-thread e is two contiguous runs of 32 -> float4
            const float4* q0 = (const float4*)(d2 + (r << 5));
            const float4* q1 = (const float4*)(d2 + 1024 + (r << 5));
            #pragma unroll
            for (int qq = 0; qq < 8; ++qq) {
                float4 a = q0[qq];
                v[4*qq+0] *= a.x * s; v[4*qq+1] *= a.y * s;
                v[4*qq+2] *= a.z * s; v[4*qq+3] *= a.w * s;
                float4 cc = q1[qq];
                v[32+4*qq+0] *= cc.x * s; v[32+4*qq+1] *= cc.y * s;
                v[32+4*qq+2] *= cc.z * s; v[32+4*qq+3] *= cc.w * s;
            }
        }
        BFLY(1) BFLY(2) BFLY(4) BFLY(8) BFLY(16) BFLY(32) // F2 e-bits 0..4,10

        // ---- T2: partition e-bit0 (= j0 on both sides). e' = e >> 1 ----
        #pragma unroll
        for (int j = 0; j < 64; j += 2)                   // round A write (e0=0)
            lds[(sw2(((j >> 1) & 15) | (r << 4) | ((j >> 5) << 9)) << 3) + tt] = v[j];
        __syncthreads();
        #pragma unroll
        for (int j = 0; j < 64; j += 2)                   // round A read: P3 map
            v[j] = lds[(sw2((((j >> 1) & 31) << 4) | (r & 15) | ((r >> 4) << 9)) << 3) + tt];
        __syncthreads();
        #pragma unroll
        for (int j = 1; j < 64; j += 2)                   // round B write (e0=1)
            lds[(sw2(((j >> 1) & 15) | (r << 4) | ((j >> 5) << 9)) << 3) + tt] = v[j];
        __syncthreads();
        #pragma unroll
        for (int j = 1; j < 64; j += 2)                   // round B read
            v[j] = lds[(sw2((((j >> 1) & 31) << 4) | (r & 15) | ((r >> 4) << 9)) << 3) + tt];
        __syncthreads();

        // ---- P3: e = ((j>>1)<<5) | (j&1) | eRest, eRest = ((r&15)<<1)|((r>>4)<<10)
        BFLY(2) BFLY(4) BFLY(8) BFLY(16) BFLY(32)         // F2 e-bits 5..9 (F2 done)
        {   // * d3 * s : (v[2m], v[2m+1]) sit at (e, e+1) -> float2
            const int eRest = ((r & 15) << 1) | ((r >> 4) << 10);
            #pragma unroll
            for (int m = 0; m < 32; ++m) {
                float2 a = *(const float2*)(d3 + ((m << 5) | eRest));
                v[2*m]   *= a.x * s;
                v[2*m+1] *= a.y * s;
            }
        }
        BFLY(2) BFLY(4) BFLY(8) BFLY(16) BFLY(32) BFLY(1) // F3 e-bits 5..9, 0

        // ---- T3: partition e-bit0 (= j0 on both sides). e' = e >> 1 ----
        #pragma unroll
        for (int j = 0; j < 64; j += 2)                   // round A write (e0=0)
            lds[(sw2((((j >> 1) & 31) << 4) | (r & 15) | ((r >> 4) << 9)) << 3) + tt] = v[j];
        __syncthreads();
        #pragma unroll
        for (int j = 0; j < 64; j += 2)                   // round A read: P4(=P2) map
            v[j] = lds[(sw2(((j >> 1) & 15) | (r << 4) | ((j >> 5) << 9)) << 3) + tt];
        __syncthreads();
        #pragma unroll
        for (int j = 1; j < 64; j += 2)                   // round B write (e0=1)
            lds[(sw2((((j >> 1) & 31) << 4) | (r & 15) | ((r >> 4) << 9)) << 3) + tt] = v[j];
        __syncthreads();
        #pragma unroll
        for (int j = 1; j < 64; j += 2)                   // round B read
            v[j] = lds[(sw2(((j >> 1) & 15) | (r << 4) | ((j >> 5) << 9)) << 3) + tt];

        // ---- P4: e = (j&31) | ((j>>5)<<10) | (r<<5). F3 e-bits 1..4, 10 ----
        BFLY(2) BFLY(4) BFLY(8) BFLY(16) BFLY(32)         // F3 done

        float* ob = out + ((size_t)km << 18) + t0 + tt;
        {   // + b, store.  b is two contiguous runs of 32 -> float4
            const float4* q0 = (const float4*)(bvec + (r << 5));
            const float4* q1 = (const float4*)(bvec + 1024 + (r << 5));
            #pragma unroll
            for (int qq = 0; qq < 8; ++qq) {
                float4 a = q0[qq];
                const int e0 = (r << 5) + 4*qq;
                ob[(size_t)(e0+0) * T_DIM] = v[4*qq+0] + a.x;
                ob[(size_t)(e0+1) * T_DIM] = v[4*qq+1] + a.y;
                ob[(size_t)(e0+2) * T_DIM] = v[4*qq+2] + a.z;
                ob[(size_t)(e0+3) * T_DIM] = v[4*qq+3] + a.w;
                float4 cc = q1[qq];
                const int e1 = 1024 + (r << 5) + 4*qq;
                ob[(size_t)(e1+0) * T_DIM] = v[32+4*qq+0] + cc.x;
                ob[(size_t)(e1+1) * T_DIM] = v[32+4*qq+1] + cc.y;
                ob[(size_t)(e1+2) * T_DIM] = v[32+4*qq+2] + cc.z;
                ob[(size_t)(e1+3) * T_DIM] = v[32+4*qq+3] + cc.w;
            }
        }
    }
}

extern "C" void kernel_launch(void* const* d_in, const int* in_sizes, int n_in,
                              void* d_out, int out_size, void* d_ws, size_t ws_size,
                              hipStream_t stream) {
    const float* z    = (const float*)d_in[0];
    const float* d1   = (const float*)d_in[1];
    const float* d2   = (const float*)d_in[2];
    const float* d3   = (const float*)d_in[3];
    const float* bvec = (const float*)d_in[4];
    const float* sldj = (const float*)d_in[5];
    float* out = (float*)d_out;

    // blocks 0..1023: FWHT apply (128 slabs x 8 tile-pairs, 2 passes each);
    // block 1024: sldj
    fwht_apply_kernel<<<1025, 256, 0, stream>>>(z, d1, d2, d3, bvec, sldj, out);
}